// Round 7
// baseline (301.026 us; speedup 1.0000x reference)
//
#include <hip/hip_runtime.h>
#include <hip/hip_bf16.h>

// VSSBlock: B=2 H=64 W=64 C=192 DM=384 N=16 R=12 K=4 L=4096
// R7: occupancy/latency round. S=256 segments (T=16) -> 12288 waves (1.5x slots).
//     Combine -> 3-sweep group-16 parallel scan (depth 256 -> 48), h_in written
//     in-place into Eb. in_proj outputs bf16 xbuf/zbuf (conv fetch halves).
//     Scan math (power-trick + sigmoid identity + pow16) unchanged from R6.

typedef __attribute__((ext_vector_type(8))) short short8;     // 8 bf16 = 4 VGPRs
typedef __attribute__((ext_vector_type(4))) float floatx4;    // fp32 accum frag

// ---------------- LayerNorm (pre-norm, eps 1e-6), C=192 -> bf16 ----------------
__global__ __launch_bounds__(256) void k_ln(const float* __restrict__ in,
                                            const float* __restrict__ g,
                                            const float* __restrict__ be,
                                            __hip_bfloat16* __restrict__ out) {
  int row = blockIdx.x * 4 + (threadIdx.x >> 6);
  int lane = threadIdx.x & 63;
  const float* x = in + (long)row * 192;
  float v0 = x[lane], v1 = x[lane + 64], v2 = x[lane + 128];
  float s = v0 + v1 + v2;
  float s2 = v0 * v0 + v1 * v1 + v2 * v2;
  #pragma unroll
  for (int o = 32; o > 0; o >>= 1) { s += __shfl_xor(s, o); s2 += __shfl_xor(s2, o); }
  float mu = s * (1.f / 192.f);
  float var = s2 * (1.f / 192.f) - mu * mu;
  float r = rsqrtf(var + 1e-6f);
  __hip_bfloat16* op = out + (long)row * 192;
  op[lane]       = __float2bfloat16((v0 - mu) * r * g[lane]       + be[lane]);
  op[lane + 64]  = __float2bfloat16((v1 - mu) * r * g[lane + 64]  + be[lane + 64]);
  op[lane + 128] = __float2bfloat16((v2 - mu) * r * g[lane + 128] + be[lane + 128]);
}

// ---------------- pack weights -> bf16, transposed to (N x K) ----------------
__global__ __launch_bounds__(256) void k_packw(const float* __restrict__ ipw,
                                               const float* __restrict__ xpw,
                                               const float* __restrict__ opw,
                                               __hip_bfloat16* __restrict__ Wt1,
                                               __hip_bfloat16* __restrict__ Wt2,
                                               __hip_bfloat16* __restrict__ Wt3) {
  int idx = blockIdx.x * 256 + threadIdx.x;
  if (idx < 147456) {                       // Wt1[n][k] = ipw[k][n]
    int n = idx / 192, k = idx - n * 192;
    Wt1[idx] = __float2bfloat16(ipw[(long)k * 768 + n]);
  } else if (idx < 147456 + 73728) {        // Wt2[j][d]
    int t = idx - 147456;
    int j = t / 384;
    float v = (j < 176) ? xpw[t] : 0.f;
    Wt2[t] = __float2bfloat16(v);
  } else if (idx < 147456 + 73728 + 73728) {// Wt3[n][k] = opw[k][n]
    int t = idx - 147456 - 73728;
    int n = t / 384, k = t - n * 384;
    Wt3[t] = __float2bfloat16(opw[(long)k * 192 + n]);
  }
}

// inverse/forward direction map (involutions): pixel p <-> scan position l
__device__ __forceinline__ int inv_dir(int k, int p) {
  int pt = ((p & 63) << 6) | (p >> 6);
  if (k == 0) return p;
  if (k == 1) return pt;
  if (k == 2) return 4095 - p;
  return 4095 - pt;
}
__device__ __forceinline__ int dir_pix(int k, int l) { return inv_dir(k, l); }

// ---------------- bf16 MFMA GEMM, 128x64 tile, BK=32; epilogue variants ----------------
// EPI 0: plain fp32 store; EPI 1: fp32 + Res; EPI 2: split bf16 -> CoB/Co2B [N=768];
// EPI 3: scatter to scan-ordered dtsS/BsS/CsS, cols>=176 dropped [N=192].
template <int EPI>
__global__ __launch_bounds__(256) void k_gemm_mfma(const __hip_bfloat16* __restrict__ A,
                                                   const __hip_bfloat16* __restrict__ Bt,
                                                   const float* __restrict__ Res,
                                                   float* __restrict__ Co,
                                                   __hip_bfloat16* __restrict__ CoB,
                                                   __hip_bfloat16* __restrict__ Co2B,
                                                   float* __restrict__ dtsS,
                                                   float* __restrict__ BsS,
                                                   float* __restrict__ CsS,
                                                   int M, int N, int Kk) {
  __shared__ __align__(16) short As[128 * 32];
  __shared__ __align__(16) short Bs[64 * 32];
  int tid = threadIdx.x;
  int wave = tid >> 6, lane = tid & 63;
  int mlane = lane & 15, quad = lane >> 4;
  int row0 = blockIdx.y * 128, col0 = blockIdx.x * 64;
  int wr = wave & 1, wc = wave >> 1;
  floatx4 acc[4][2];
  #pragma unroll
  for (int mi = 0; mi < 4; mi++)
    #pragma unroll
    for (int ni = 0; ni < 2; ni++) acc[mi][ni] = (floatx4){0.f, 0.f, 0.f, 0.f};

  for (int k0 = 0; k0 < Kk; k0 += 32) {
    #pragma unroll
    for (int c = tid; c < 512; c += 256) {
      int r = c >> 2, off = (c & 3) * 8;
      *(float4*)&As[r * 32 + off] = *(const float4*)&A[(long)(row0 + r) * Kk + k0 + off];
    }
    {
      int c = tid;
      int r = c >> 2, off = (c & 3) * 8;
      *(float4*)&Bs[r * 32 + off] = *(const float4*)&Bt[(long)(col0 + r) * Kk + k0 + off];
    }
    __syncthreads();
    short8 af[4], bf[2];
    #pragma unroll
    for (int mi = 0; mi < 4; mi++)
      af[mi] = *(const short8*)&As[(wr * 64 + mi * 16 + mlane) * 32 + quad * 8];
    #pragma unroll
    for (int ni = 0; ni < 2; ni++)
      bf[ni] = *(const short8*)&Bs[(wc * 32 + ni * 16 + mlane) * 32 + quad * 8];
    #pragma unroll
    for (int mi = 0; mi < 4; mi++)
      #pragma unroll
      for (int ni = 0; ni < 2; ni++)
        acc[mi][ni] = __builtin_amdgcn_mfma_f32_16x16x32_bf16(af[mi], bf[ni], acc[mi][ni], 0, 0, 0);
    __syncthreads();
  }
  // C/D layout: col=lane&15, row=quad*4+reg  [m89-verified]
  #pragma unroll
  for (int mi = 0; mi < 4; mi++) {
    #pragma unroll
    for (int ni = 0; ni < 2; ni++) {
      int cc = col0 + wc * 32 + ni * 16 + mlane;
      #pragma unroll
      for (int i = 0; i < 4; i++) {
        int rr = row0 + wr * 64 + mi * 16 + quad * 4 + i;
        float v = acc[mi][ni][i];
        if (EPI == 0) {
          Co[(long)rr * N + cc] = v;
        } else if (EPI == 1) {
          Co[(long)rr * N + cc] = v + Res[(long)rr * N + cc];
        } else if (EPI == 2) {
          if (cc < 384) CoB[(long)rr * 384 + cc] = __float2bfloat16(v);
          else          Co2B[(long)rr * 384 + (cc - 384)] = __float2bfloat16(v);
        } else {  // EPI == 3
          if (cc < 176) {
            int k4 = (cc >= 132) ? 3 : (cc >= 88) ? 2 : (cc >= 44) ? 1 : 0;
            int c = cc - k4 * 44;
            int b = rr >> 12, p = rr & 4095;
            int l = inv_dir(k4, p);
            long lbase = ((long)((b << 2) + k4) << 12) + l;
            if (c < 12)      dtsS[lbase * 12 + c] = v;
            else if (c < 28) BsS[lbase * 16 + (c - 12)] = v;
            else             CsS[lbase * 16 + (c - 28)] = v;
          }
        }
      }
    }
  }
}

// ---------------- depthwise 3x3 conv + bias + SiLU; reads bf16 xbuf ----------------
__global__ __launch_bounds__(384) void k_conv(const __hip_bfloat16* __restrict__ xbufB,
                                              const float* __restrict__ cw,
                                              const float* __restrict__ cb,
                                              float* __restrict__ xc,
                                              __hip_bfloat16* __restrict__ xcb) {
  int row = blockIdx.x;
  int b = row >> 12, p = row & 4095;
  int h = p >> 6, w0 = p & 63;
  int d = threadIdx.x;
  float acc = cb[d];
  const float* wt = cw + d * 9;
  #pragma unroll
  for (int dh = -1; dh <= 1; dh++) {
    int hh = h + dh;
    if (hh < 0 || hh > 63) continue;
    #pragma unroll
    for (int dw = -1; dw <= 1; dw++) {
      int ww = w0 + dw;
      if (ww < 0 || ww > 63) continue;
      acc += __bfloat162float(xbufB[((long)(b << 12) + (hh << 6) + ww) * 384 + d])
             * wt[(dh + 1) * 3 + (dw + 1)];
    }
  }
  float sg = 1.f / (1.f + __expf(-acc));
  float v = acc * sg;
  xc[(long)row * 384 + d] = v;
  xcb[(long)row * 384 + d] = __float2bfloat16(v);
}

// powers: pws[n] = r^(n+1), log-depth pairing
__device__ __forceinline__ void pow16(float r, float* pws) {
  pws[0] = r;
  #pragma unroll
  for (int n = 1; n < 16; n++) {
    int m = n + 1, c = (m + 1) / 2, f = m - c;
    pws[n] = pws[c - 1] * pws[f - 1];
  }
}

// ---------------- scan pass 0: 256 segments x 16 steps; E[16] + scalar cumDelta ----------------
__global__ __launch_bounds__(384) void k_scan0(
    const float* __restrict__ dtsS, const float* __restrict__ BsS,
    const float* __restrict__ xc,
    const float* __restrict__ A_logs, const float* __restrict__ dt_w,
    const float* __restrict__ dt_b,
    float* __restrict__ EHb, float* __restrict__ Dend) {
  int bid = blockIdx.x;
  int s = bid & 255, bk = bid >> 8;
  int k = bk & 3, b = bk >> 2;
  int d = threadIdx.x;
  float w[12];
  const float* dwp = dt_w + ((long)(k * 384) + d) * 12;
  #pragma unroll
  for (int r = 0; r < 12; r++) w[r] = dwp[r];
  float db = dt_b[k * 384 + d];
  const float* al = A_logs + ((long)(k * 384) + d) * 16;
  bool pw = true;
  float av[16];
  #pragma unroll
  for (int n = 0; n < 16; n++) {
    float a = __expf(al[n]);
    av[n] = -a;
    pw = pw && (fabsf(a - (float)(n + 1)) < 1e-3f);
  }
  float h[16];
  #pragma unroll
  for (int n = 0; n < 16; n++) h[n] = 0.f;
  float cum = 0.f;
  long lb = (long)bk * 4096 + s * 16;
  long bpix = (long)(b << 12);

  if (pw) {
    #pragma unroll 4
    for (int t = 0; t < 16; t++) {
      const float4* dq = (const float4*)(dtsS + (lb + t) * 12);
      float4 q0 = dq[0], q1 = dq[1], q2 = dq[2];
      float x = db + q0.x * w[0] + q0.y * w[1] + q0.z * w[2] + q0.w * w[3]
                   + q1.x * w[4] + q1.y * w[5] + q1.z * w[6] + q1.w * w[7]
                   + q2.x * w[8] + q2.y * w[9] + q2.z * w[10] + q2.w * w[11];
      float e = __expf(x);
      float delta = (x > 15.f) ? x : __logf(1.f + e);
      cum += delta;
      int p = dir_pix(k, s * 16 + t);
      float u = xc[(bpix + p) * 384 + d];
      float du = delta * u;
      float rr = __builtin_amdgcn_rcpf(1.f + e);  // exp(-softplus(x))
      float pws[16]; pow16(rr, pws);
      const float4* Bq = (const float4*)(BsS + (lb + t) * 16);
      float4 b0 = Bq[0], b1 = Bq[1], b2 = Bq[2], b3 = Bq[3];
      float Bl[16] = {b0.x, b0.y, b0.z, b0.w, b1.x, b1.y, b1.z, b1.w,
                      b2.x, b2.y, b2.z, b2.w, b3.x, b3.y, b3.z, b3.w};
      #pragma unroll
      for (int n = 0; n < 16; n++) h[n] = pws[n] * h[n] + du * Bl[n];
    }
  } else {
    for (int t = 0; t < 16; t++) {
      const float4* dq = (const float4*)(dtsS + (lb + t) * 12);
      float4 q0 = dq[0], q1 = dq[1], q2 = dq[2];
      float x = db + q0.x * w[0] + q0.y * w[1] + q0.z * w[2] + q0.w * w[3]
                   + q1.x * w[4] + q1.y * w[5] + q1.z * w[6] + q1.w * w[7]
                   + q2.x * w[8] + q2.y * w[9] + q2.z * w[10] + q2.w * w[11];
      float e = __expf(x);
      float delta = (x > 15.f) ? x : __logf(1.f + e);
      cum += delta;
      int p = dir_pix(k, s * 16 + t);
      float u = xc[(bpix + p) * 384 + d];
      float du = delta * u;
      const float4* Bq = (const float4*)(BsS + (lb + t) * 16);
      float4 b0 = Bq[0], b1 = Bq[1], b2 = Bq[2], b3 = Bq[3];
      float Bl[16] = {b0.x, b0.y, b0.z, b0.w, b1.x, b1.y, b1.z, b1.w,
                      b2.x, b2.y, b2.z, b2.w, b3.x, b3.y, b3.z, b3.w};
      #pragma unroll
      for (int n = 0; n < 16; n++) {
        float dA = __expf(delta * av[n]);
        h[n] = dA * h[n] + du * Bl[n];
      }
    }
  }
  long g = (long)bk * 256 + s;
  float* Ep = EHb + g * 6144 + d * 16;
  #pragma unroll
  for (int n = 0; n < 16; n++) Ep[n] = h[n];
  Dend[g * 384 + d] = cum;
}

// ---------------- combine sweep 1: per-16-seg group affine aggregate (Gp, Ge) ----------------
// block = ((chain*16+group)*24 + dnblk), 256 threads over dn
__global__ __launch_bounds__(256) void k_comb1(const float* __restrict__ EHb,
                                               const float* __restrict__ Dend,
                                               const float* __restrict__ A_logs,
                                               float* __restrict__ Gp,
                                               float* __restrict__ Ge) {
  int bid = blockIdx.x;
  int dnblk = bid % 24;
  int cg = bid / 24;
  int group = cg & 15, chain = cg >> 4;
  int dn = dnblk * 256 + threadIdx.x;
  int k = chain & 3, d = dn >> 4;
  float av = -__expf(A_logs[(long)k * 6144 + dn]);
  float P = 1.f, Eacc = 0.f;
  long s0 = (long)chain * 256 + group * 16;
  for (int i = 0; i < 16; i++) {
    long s = s0 + i;
    float p = __expf(av * Dend[s * 384 + d]);
    float e = EHb[s * 6144 + dn];
    P *= p;
    Eacc = p * Eacc + e;
  }
  Gp[(long)cg * 6144 + dn] = P;
  Ge[(long)cg * 6144 + dn] = Eacc;
}

// ---------------- combine sweep 2: serial exclusive prefix over 16 groups ----------------
__global__ __launch_bounds__(256) void k_comb2(const float* __restrict__ Gp,
                                               const float* __restrict__ Ge,
                                               float* __restrict__ Gh) {
  int t = blockIdx.x * 256 + threadIdx.x;  // 8*6144 = 49152
  int chain = t / 6144;
  int dn = t - chain * 6144;
  float h = 0.f;
  for (int g2 = 0; g2 < 16; g2++) {
    long idx = ((long)chain * 16 + g2) * 6144 + dn;
    float P = Gp[idx], E = Ge[idx];
    Gh[idx] = h;
    h = P * h + E;
  }
}

// ---------------- combine sweep 3: re-walk group, write h_in in-place into EHb ----------------
__global__ __launch_bounds__(256) void k_comb3(float* __restrict__ EHb,
                                               const float* __restrict__ Dend,
                                               const float* __restrict__ A_logs,
                                               const float* __restrict__ Gh) {
  int bid = blockIdx.x;
  int dnblk = bid % 24;
  int cg = bid / 24;
  int group = cg & 15, chain = cg >> 4;
  int dn = dnblk * 256 + threadIdx.x;
  int k = chain & 3, d = dn >> 4;
  float av = -__expf(A_logs[(long)k * 6144 + dn]);
  float h = Gh[(long)cg * 6144 + dn];
  long s0 = (long)chain * 256 + group * 16;
  for (int i = 0; i < 16; i++) {
    long s = s0 + i;
    float p = __expf(av * Dend[s * 384 + d]);
    float e = EHb[s * 6144 + dn];   // read E before overwrite
    EHb[s * 6144 + dn] = h;         // h_in for segment s
    h = p * h + e;
  }
}

// ---------------- scan pass 1: full recurrence from h_in (in EHb), atomicAdd y ----------------
__global__ __launch_bounds__(384) void k_scan1(
    const float* __restrict__ dtsS, const float* __restrict__ BsS,
    const float* __restrict__ CsS, const float* __restrict__ xc,
    const float* __restrict__ A_logs, const float* __restrict__ dt_w,
    const float* __restrict__ dt_b, const float* __restrict__ EHb,
    float* __restrict__ ysum) {
  int bid = blockIdx.x;
  int s = bid & 255, bk = bid >> 8;
  int k = bk & 3, b = bk >> 2;
  int d = threadIdx.x;
  float w[12];
  const float* dwp = dt_w + ((long)(k * 384) + d) * 12;
  #pragma unroll
  for (int r = 0; r < 12; r++) w[r] = dwp[r];
  float db = dt_b[k * 384 + d];
  const float* al = A_logs + ((long)(k * 384) + d) * 16;
  bool pw = true;
  float av[16];
  #pragma unroll
  for (int n = 0; n < 16; n++) {
    float a = __expf(al[n]);
    av[n] = -a;
    pw = pw && (fabsf(a - (float)(n + 1)) < 1e-3f);
  }
  float h[16];
  const float* hp = EHb + ((long)bk * 256 + s) * 6144 + d * 16;
  #pragma unroll
  for (int n = 0; n < 16; n++) h[n] = hp[n];
  long lb = (long)bk * 4096 + s * 16;
  long bpix = (long)(b << 12);

  if (pw) {
    #pragma unroll 4
    for (int t = 0; t < 16; t++) {
      const float4* dq = (const float4*)(dtsS + (lb + t) * 12);
      float4 q0 = dq[0], q1 = dq[1], q2 = dq[2];
      float x = db + q0.x * w[0] + q0.y * w[1] + q0.z * w[2] + q0.w * w[3]
                   + q1.x * w[4] + q1.y * w[5] + q1.z * w[6] + q1.w * w[7]
                   + q2.x * w[8] + q2.y * w[9] + q2.z * w[10] + q2.w * w[11];
      float e = __expf(x);
      float delta = (x > 15.f) ? x : __logf(1.f + e);
      int p = dir_pix(k, s * 16 + t);
      float u = xc[(bpix + p) * 384 + d];
      float du = delta * u;
      float rr = __builtin_amdgcn_rcpf(1.f + e);
      float pws[16]; pow16(rr, pws);
      const float4* Bq = (const float4*)(BsS + (lb + t) * 16);
      float4 b0 = Bq[0], b1 = Bq[1], b2 = Bq[2], b3 = Bq[3];
      float Bl[16] = {b0.x, b0.y, b0.z, b0.w, b1.x, b1.y, b1.z, b1.w,
                      b2.x, b2.y, b2.z, b2.w, b3.x, b3.y, b3.z, b3.w};
      const float4* Cq = (const float4*)(CsS + (lb + t) * 16);
      float4 c0 = Cq[0], c1 = Cq[1], c2 = Cq[2], c3 = Cq[3];
      float Cl[16] = {c0.x, c0.y, c0.z, c0.w, c1.x, c1.y, c1.z, c1.w,
                      c2.x, c2.y, c2.z, c2.w, c3.x, c3.y, c3.z, c3.w};
      float y = 0.f;
      #pragma unroll
      for (int n = 0; n < 16; n++) { h[n] = pws[n] * h[n] + du * Bl[n]; y += h[n] * Cl[n]; }
      atomicAdd(&ysum[(bpix + p) * 384 + d], y);
    }
  } else {
    for (int t = 0; t < 16; t++) {
      const float4* dq = (const float4*)(dtsS + (lb + t) * 12);
      float4 q0 = dq[0], q1 = dq[1], q2 = dq[2];
      float x = db + q0.x * w[0] + q0.y * w[1] + q0.z * w[2] + q0.w * w[3]
                   + q1.x * w[4] + q1.y * w[5] + q1.z * w[6] + q1.w * w[7]
                   + q2.x * w[8] + q2.y * w[9] + q2.z * w[10] + q2.w * w[11];
      float e = __expf(x);
      float delta = (x > 15.f) ? x : __logf(1.f + e);
      int p = dir_pix(k, s * 16 + t);
      float u = xc[(bpix + p) * 384 + d];
      float du = delta * u;
      const float4* Bq = (const float4*)(BsS + (lb + t) * 16);
      float4 b0 = Bq[0], b1 = Bq[1], b2 = Bq[2], b3 = Bq[3];
      float Bl[16] = {b0.x, b0.y, b0.z, b0.w, b1.x, b1.y, b1.z, b1.w,
                      b2.x, b2.y, b2.z, b2.w, b3.x, b3.y, b3.z, b3.w};
      const float4* Cq = (const float4*)(CsS + (lb + t) * 16);
      float4 c0 = Cq[0], c1 = Cq[1], c2 = Cq[2], c3 = Cq[3];
      float Cl[16] = {c0.x, c0.y, c0.z, c0.w, c1.x, c1.y, c1.z, c1.w,
                      c2.x, c2.y, c2.z, c2.w, c3.x, c3.y, c3.z, c3.w};
      float y = 0.f;
      #pragma unroll
      for (int n = 0; n < 16; n++) {
        float dA = __expf(delta * av[n]);
        h[n] = dA * h[n] + du * Bl[n];
        y += h[n] * Cl[n];
      }
      atomicAdd(&ysum[(bpix + p) * 384 + d], y);
    }
  }
}

// ---------------- merge: ysum + D-skip + out-LN + silu(z bf16) -> bf16 yact ----------------
__global__ __launch_bounds__(384) void k_merge(const float* __restrict__ ysum,
                                               const float* __restrict__ xc,
                                               const __hip_bfloat16* __restrict__ zbufB,
                                               const float* __restrict__ Ds,
                                               const float* __restrict__ g,
                                               const float* __restrict__ be,
                                               __hip_bfloat16* __restrict__ yactb) {
  int row = blockIdx.x;
  int d = threadIdx.x;
  float v = ysum[(long)row * 384 + d];
  float sd = Ds[d] + Ds[384 + d] + Ds[768 + d] + Ds[1152 + d];
  v += xc[(long)row * 384 + d] * sd;
  float s1 = v, s2 = v * v;
  #pragma unroll
  for (int o = 32; o > 0; o >>= 1) { s1 += __shfl_xor(s1, o); s2 += __shfl_xor(s2, o); }
  __shared__ float r1[6], r2[6];
  int wv = threadIdx.x >> 6;
  if ((threadIdx.x & 63) == 0) { r1[wv] = s1; r2[wv] = s2; }
  __syncthreads();
  float S1 = 0.f, S2 = 0.f;
  #pragma unroll
  for (int i = 0; i < 6; i++) { S1 += r1[i]; S2 += r2[i]; }
  float mu = S1 * (1.f / 384.f);
  float var = S2 * (1.f / 384.f) - mu * mu;
  float rr = rsqrtf(var + 1e-5f);
  float yn = (v - mu) * rr * g[d] + be[d];
  float z = __bfloat162float(zbufB[(long)row * 384 + d]);
  float sg = z / (1.f + __expf(-z));
  yactb[(long)row * 384 + d] = __float2bfloat16(yn * sg);
}

extern "C" void kernel_launch(void* const* d_in, const int* in_sizes, int n_in,
                              void* d_out, int out_size, void* d_ws, size_t ws_size,
                              hipStream_t stream) {
  const float* input      = (const float*)d_in[0];
  const float* norm_g     = (const float*)d_in[1];
  const float* norm_b     = (const float*)d_in[2];
  const float* in_proj_w  = (const float*)d_in[3];
  const float* conv_w     = (const float*)d_in[4];
  const float* conv_b     = (const float*)d_in[5];
  const float* x_proj_w   = (const float*)d_in[6];
  const float* dt_w       = (const float*)d_in[7];
  const float* dt_b       = (const float*)d_in[8];
  const float* A_logs     = (const float*)d_in[9];
  const float* Ds         = (const float*)d_in[10];
  const float* out_norm_g = (const float*)d_in[11];
  const float* out_norm_b = (const float*)d_in[12];
  const float* out_proj_w = (const float*)d_in[13];
  float* out = (float*)d_out;

  float* ws = (float*)d_ws;
  long o = 0;
  __hip_bfloat16* xnb   = (__hip_bfloat16*)(ws + o); o += 393216;   // 8192x192 bf16
  __hip_bfloat16* xbufB = (__hip_bfloat16*)(ws + o); o += 1572864;  // 8192x384 bf16
  __hip_bfloat16* zbufB = (__hip_bfloat16*)(ws + o); o += 1572864;  // 8192x384 bf16
  float* xc             = ws + o;                    o += 3145728;  // 8192x384 fp32
  __hip_bfloat16* xcb   = (__hip_bfloat16*)(ws + o); o += 1572864;  // 8192x384 bf16
  __hip_bfloat16* Wt1   = (__hip_bfloat16*)(ws + o); o += 73728;
  __hip_bfloat16* Wt2   = (__hip_bfloat16*)(ws + o); o += 36864;
  __hip_bfloat16* Wt3   = (__hip_bfloat16*)(ws + o); o += 36864;
  float* dtsS           = ws + o;                    o += 393216;   // (BK,L,12)
  float* BsS            = ws + o;                    o += 524288;   // (BK,L,16)
  float* CsS            = ws + o;                    o += 524288;
  float* EHb            = ws + o;                    o += 12582912; // (2048 segs, 6144) E then h_in
  float* Dend           = ws + o;                    o += 786432;   // (2048, 384)
  float* Gp             = ws + o;                    o += 786432;   // (128 cg, 6144)
  float* Ge             = ws + o;                    o += 786432;
  float* Gh             = ws + o;                    o += 786432;
  float* ysum           = ws + o;                    o += 3145728;
  __hip_bfloat16* yactb = (__hip_bfloat16*)(ws + o); o += 1572864;
  // total ≈ 30.3M floats ≈ 121 MB

  k_ln<<<dim3(2048), dim3(256), 0, stream>>>(input, norm_g, norm_b, xnb);
  k_packw<<<dim3(1152), dim3(256), 0, stream>>>(in_proj_w, x_proj_w, out_proj_w, Wt1, Wt2, Wt3);
  // in_proj: (8192x192)@(192x768), split bf16 epilogue -> xbufB/zbufB
  k_gemm_mfma<2><<<dim3(12, 64), dim3(256), 0, stream>>>(xnb, Wt1, nullptr, nullptr, xbufB, zbufB,
                                                         nullptr, nullptr, nullptr, 8192, 768, 192);
  k_conv<<<dim3(8192), dim3(384), 0, stream>>>(xbufB, conv_w, conv_b, xc, xcb);
  // x_proj: (8192x384)@(384x192), scatter epilogue -> dtsS/BsS/CsS (scan order)
  k_gemm_mfma<3><<<dim3(3, 64), dim3(256), 0, stream>>>(xcb, Wt2, nullptr, nullptr, nullptr, nullptr,
                                                        dtsS, BsS, CsS, 8192, 192, 384);
  k_scan0<<<dim3(2048), dim3(384), 0, stream>>>(dtsS, BsS, xc, A_logs, dt_w, dt_b, EHb, Dend);
  k_comb1<<<dim3(3072), dim3(256), 0, stream>>>(EHb, Dend, A_logs, Gp, Ge);
  k_comb2<<<dim3(192), dim3(256), 0, stream>>>(Gp, Ge, Gh);
  k_comb3<<<dim3(3072), dim3(256), 0, stream>>>(EHb, Dend, A_logs, Gh);
  hipMemsetAsync(ysum, 0, 3145728 * sizeof(float), stream);
  k_scan1<<<dim3(2048), dim3(384), 0, stream>>>(dtsS, BsS, CsS, xc, A_logs, dt_w, dt_b, EHb, ysum);
  k_merge<<<dim3(8192), dim3(384), 0, stream>>>(ysum, xc, zbufB, Ds, out_norm_g, out_norm_b, yactb);
  // out_proj + residual: (8192x384)@(384x192) + input
  k_gemm_mfma<1><<<dim3(3, 64), dim3(256), 0, stream>>>(yactb, Wt3, input, out, nullptr, nullptr,
                                                        nullptr, nullptr, nullptr, 8192, 192, 384);
}

// Round 8
// 270.241 us; speedup vs baseline: 1.1139x; 1.1139x over previous
//
#include <hip/hip_runtime.h>
#include <hip/hip_bf16.h>

// VSSBlock: B=2 H=64 W=64 C=192 DM=384 N=16 R=12 K=4 L=4096
// R8: GEMM rework (64x64 tile, BK=64, XOR-swizzled LDS -> 2-way-free bank access,
//     384..1536-block grids); scan back to S=128/T=32 with single in-place combine;
//     xc kept ONLY as bf16 (scan + merge read xcb); 11 dispatches.

typedef __attribute__((ext_vector_type(8))) short short8;     // 8 bf16 = 4 VGPRs
typedef __attribute__((ext_vector_type(4))) float floatx4;    // fp32 accum frag

// ---------------- LayerNorm (pre-norm, eps 1e-6), C=192 -> bf16 ----------------
__global__ __launch_bounds__(256) void k_ln(const float* __restrict__ in,
                                            const float* __restrict__ g,
                                            const float* __restrict__ be,
                                            __hip_bfloat16* __restrict__ out) {
  int row = blockIdx.x * 4 + (threadIdx.x >> 6);
  int lane = threadIdx.x & 63;
  const float* x = in + (long)row * 192;
  float v0 = x[lane], v1 = x[lane + 64], v2 = x[lane + 128];
  float s = v0 + v1 + v2;
  float s2 = v0 * v0 + v1 * v1 + v2 * v2;
  #pragma unroll
  for (int o = 32; o > 0; o >>= 1) { s += __shfl_xor(s, o); s2 += __shfl_xor(s2, o); }
  float mu = s * (1.f / 192.f);
  float var = s2 * (1.f / 192.f) - mu * mu;
  float r = rsqrtf(var + 1e-6f);
  __hip_bfloat16* op = out + (long)row * 192;
  op[lane]       = __float2bfloat16((v0 - mu) * r * g[lane]       + be[lane]);
  op[lane + 64]  = __float2bfloat16((v1 - mu) * r * g[lane + 64]  + be[lane + 64]);
  op[lane + 128] = __float2bfloat16((v2 - mu) * r * g[lane + 128] + be[lane + 128]);
}

// ---------------- pack weights -> bf16, transposed to (N x K) ----------------
__global__ __launch_bounds__(256) void k_packw(const float* __restrict__ ipw,
                                               const float* __restrict__ xpw,
                                               const float* __restrict__ opw,
                                               __hip_bfloat16* __restrict__ Wt1,
                                               __hip_bfloat16* __restrict__ Wt2,
                                               __hip_bfloat16* __restrict__ Wt3) {
  int idx = blockIdx.x * 256 + threadIdx.x;
  if (idx < 147456) {                       // Wt1[n][k] = ipw[k][n]
    int n = idx / 192, k = idx - n * 192;
    Wt1[idx] = __float2bfloat16(ipw[(long)k * 768 + n]);
  } else if (idx < 147456 + 73728) {        // Wt2[j][d]
    int t = idx - 147456;
    int j = t / 384;
    float v = (j < 176) ? xpw[t] : 0.f;
    Wt2[t] = __float2bfloat16(v);
  } else if (idx < 147456 + 73728 + 73728) {// Wt3[n][k] = opw[k][n]
    int t = idx - 147456 - 73728;
    int n = t / 384, k = t - n * 384;
    Wt3[t] = __float2bfloat16(opw[(long)k * 192 + n]);
  }
}

// direction map (involutions): pixel p <-> scan position l
__device__ __forceinline__ int inv_dir(int k, int p) {
  int pt = ((p & 63) << 6) | (p >> 6);
  if (k == 0) return p;
  if (k == 1) return pt;
  if (k == 2) return 4095 - p;
  return 4095 - pt;
}
__device__ __forceinline__ int dir_pix(int k, int l) { return inv_dir(k, l); }

// ---------------- bf16 MFMA GEMM: 64x64 tile, BK=64, XOR-swizzled LDS ----------------
// 4 waves 2x2; wave tile 32x32 = 2x2 frags of 16x16x32, 2 k-steps per iter.
// LDS rows: 64 shorts (8 chunks of 16B); chunk j of row r stored at j^(r&7)
// -> ds_read_b128 per quad hits 8 distinct bank groups (2-way = free, m136).
// EPI 1: fp32 + Res; EPI 2: split bf16 -> CoB/Co2B [N=768]; EPI 3: scatter scan-order.
template <int EPI>
__global__ __launch_bounds__(256) void k_gemm_mfma(const __hip_bfloat16* __restrict__ A,
                                                   const __hip_bfloat16* __restrict__ Bt,
                                                   const float* __restrict__ Res,
                                                   float* __restrict__ Co,
                                                   __hip_bfloat16* __restrict__ CoB,
                                                   __hip_bfloat16* __restrict__ Co2B,
                                                   float* __restrict__ dtsS,
                                                   float* __restrict__ BsS,
                                                   float* __restrict__ CsS,
                                                   int M, int N, int Kk) {
  __shared__ __align__(16) short As[64 * 64];
  __shared__ __align__(16) short Bs[64 * 64];
  int tid = threadIdx.x;
  int wave = tid >> 6, lane = tid & 63;
  int mlane = lane & 15, quad = lane >> 4;
  int row0 = blockIdx.y * 64, col0 = blockIdx.x * 64;
  int wr = wave & 1, wc = wave >> 1;
  floatx4 acc[2][2];
  #pragma unroll
  for (int mi = 0; mi < 2; mi++)
    #pragma unroll
    for (int ni = 0; ni < 2; ni++) acc[mi][ni] = (floatx4){0.f, 0.f, 0.f, 0.f};

  for (int k0 = 0; k0 < Kk; k0 += 64) {
    #pragma unroll
    for (int c = tid; c < 512; c += 256) {
      int r = c >> 3, j = c & 7;
      *(float4*)&As[r * 64 + ((j ^ (r & 7)) << 3)] =
          *(const float4*)&A[(long)(row0 + r) * Kk + k0 + j * 8];
    }
    #pragma unroll
    for (int c = tid; c < 512; c += 256) {
      int r = c >> 3, j = c & 7;
      *(float4*)&Bs[r * 64 + ((j ^ (r & 7)) << 3)] =
          *(const float4*)&Bt[(long)(col0 + r) * Kk + k0 + j * 8];
    }
    __syncthreads();
    short8 af[2][2], bf[2][2];
    #pragma unroll
    for (int mi = 0; mi < 2; mi++) {
      int r = wr * 32 + mi * 16 + mlane;
      #pragma unroll
      for (int kk = 0; kk < 2; kk++) {
        int jx = (kk * 4 + quad) ^ (r & 7);
        af[mi][kk] = *(const short8*)&As[r * 64 + jx * 8];
      }
    }
    #pragma unroll
    for (int ni = 0; ni < 2; ni++) {
      int rn = wc * 32 + ni * 16 + mlane;
      #pragma unroll
      for (int kk = 0; kk < 2; kk++) {
        int jx = (kk * 4 + quad) ^ (rn & 7);
        bf[ni][kk] = *(const short8*)&Bs[rn * 64 + jx * 8];
      }
    }
    #pragma unroll
    for (int kk = 0; kk < 2; kk++)
      #pragma unroll
      for (int mi = 0; mi < 2; mi++)
        #pragma unroll
        for (int ni = 0; ni < 2; ni++)
          acc[mi][ni] = __builtin_amdgcn_mfma_f32_16x16x32_bf16(af[mi][kk], bf[ni][kk],
                                                                acc[mi][ni], 0, 0, 0);
    __syncthreads();
  }
  // C/D layout: col=lane&15, row=quad*4+reg  [m89-verified]
  #pragma unroll
  for (int mi = 0; mi < 2; mi++) {
    #pragma unroll
    for (int ni = 0; ni < 2; ni++) {
      int cc = col0 + wc * 32 + ni * 16 + mlane;
      #pragma unroll
      for (int i = 0; i < 4; i++) {
        int rr = row0 + wr * 32 + mi * 16 + quad * 4 + i;
        float v = acc[mi][ni][i];
        if (EPI == 1) {
          Co[(long)rr * N + cc] = v + Res[(long)rr * N + cc];
        } else if (EPI == 2) {
          if (cc < 384) CoB[(long)rr * 384 + cc] = __float2bfloat16(v);
          else          Co2B[(long)rr * 384 + (cc - 384)] = __float2bfloat16(v);
        } else {  // EPI == 3
          if (cc < 176) {
            int k4 = (cc >= 132) ? 3 : (cc >= 88) ? 2 : (cc >= 44) ? 1 : 0;
            int c = cc - k4 * 44;
            int b = rr >> 12, p = rr & 4095;
            int l = inv_dir(k4, p);
            long lbase = ((long)((b << 2) + k4) << 12) + l;
            if (c < 12)      dtsS[lbase * 12 + c] = v;
            else if (c < 28) BsS[lbase * 16 + (c - 12)] = v;
            else             CsS[lbase * 16 + (c - 28)] = v;
          }
        }
      }
    }
  }
}

// ---------------- depthwise 3x3 conv + bias + SiLU; bf16 in, bf16 out ----------------
__global__ __launch_bounds__(384) void k_conv(const __hip_bfloat16* __restrict__ xbufB,
                                              const float* __restrict__ cw,
                                              const float* __restrict__ cb,
                                              __hip_bfloat16* __restrict__ xcb) {
  int row = blockIdx.x;
  int b = row >> 12, p = row & 4095;
  int h = p >> 6, w0 = p & 63;
  int d = threadIdx.x;
  float acc = cb[d];
  const float* wt = cw + d * 9;
  #pragma unroll
  for (int dh = -1; dh <= 1; dh++) {
    int hh = h + dh;
    if (hh < 0 || hh > 63) continue;
    #pragma unroll
    for (int dw = -1; dw <= 1; dw++) {
      int ww = w0 + dw;
      if (ww < 0 || ww > 63) continue;
      acc += __bfloat162float(xbufB[((long)(b << 12) + (hh << 6) + ww) * 384 + d])
             * wt[(dh + 1) * 3 + (dw + 1)];
    }
  }
  float sg = 1.f / (1.f + __expf(-acc));
  xcb[(long)row * 384 + d] = __float2bfloat16(acc * sg);
}

// powers: pws[n] = r^(n+1), log-depth pairing
__device__ __forceinline__ void pow16(float r, float* pws) {
  pws[0] = r;
  #pragma unroll
  for (int n = 1; n < 16; n++) {
    int m = n + 1, c = (m + 1) / 2, f = m - c;
    pws[n] = pws[c - 1] * pws[f - 1];
  }
}

// ---------------- scan pass 0: 128 segments x 32 steps; E[16] + scalar cumDelta ----------------
__global__ __launch_bounds__(384) void k_scan0(
    const float* __restrict__ dtsS, const float* __restrict__ BsS,
    const __hip_bfloat16* __restrict__ xcb,
    const float* __restrict__ A_logs, const float* __restrict__ dt_w,
    const float* __restrict__ dt_b,
    float* __restrict__ Eb, float* __restrict__ Dend) {
  int bid = blockIdx.x;
  int s = bid & 127, bk = bid >> 7;
  int k = bk & 3, b = bk >> 2;
  int d = threadIdx.x;
  float w[12];
  const float* dwp = dt_w + ((long)(k * 384) + d) * 12;
  #pragma unroll
  for (int r = 0; r < 12; r++) w[r] = dwp[r];
  float db = dt_b[k * 384 + d];
  const float* al = A_logs + ((long)(k * 384) + d) * 16;
  bool pw = true;
  float av[16];
  #pragma unroll
  for (int n = 0; n < 16; n++) {
    float a = __expf(al[n]);
    av[n] = -a;
    pw = pw && (fabsf(a - (float)(n + 1)) < 1e-3f);
  }
  float h[16];
  #pragma unroll
  for (int n = 0; n < 16; n++) h[n] = 0.f;
  float cum = 0.f;
  long lb = (long)bk * 4096 + s * 32;
  long bpix = (long)(b << 12);

  if (pw) {
    #pragma unroll 4
    for (int t = 0; t < 32; t++) {
      const float4* dq = (const float4*)(dtsS + (lb + t) * 12);
      float4 q0 = dq[0], q1 = dq[1], q2 = dq[2];
      float x = db + q0.x * w[0] + q0.y * w[1] + q0.z * w[2] + q0.w * w[3]
                   + q1.x * w[4] + q1.y * w[5] + q1.z * w[6] + q1.w * w[7]
                   + q2.x * w[8] + q2.y * w[9] + q2.z * w[10] + q2.w * w[11];
      float e = __expf(x);
      float delta = (x > 15.f) ? x : __logf(1.f + e);
      cum += delta;
      int p = dir_pix(k, s * 32 + t);
      float u = __bfloat162float(xcb[(bpix + p) * 384 + d]);
      float du = delta * u;
      float rr = __builtin_amdgcn_rcpf(1.f + e);  // exp(-softplus(x))
      float pws[16]; pow16(rr, pws);
      const float4* Bq = (const float4*)(BsS + (lb + t) * 16);
      float4 b0 = Bq[0], b1 = Bq[1], b2 = Bq[2], b3 = Bq[3];
      float Bl[16] = {b0.x, b0.y, b0.z, b0.w, b1.x, b1.y, b1.z, b1.w,
                      b2.x, b2.y, b2.z, b2.w, b3.x, b3.y, b3.z, b3.w};
      #pragma unroll
      for (int n = 0; n < 16; n++) h[n] = pws[n] * h[n] + du * Bl[n];
    }
  } else {
    for (int t = 0; t < 32; t++) {
      const float4* dq = (const float4*)(dtsS + (lb + t) * 12);
      float4 q0 = dq[0], q1 = dq[1], q2 = dq[2];
      float x = db + q0.x * w[0] + q0.y * w[1] + q0.z * w[2] + q0.w * w[3]
                   + q1.x * w[4] + q1.y * w[5] + q1.z * w[6] + q1.w * w[7]
                   + q2.x * w[8] + q2.y * w[9] + q2.z * w[10] + q2.w * w[11];
      float e = __expf(x);
      float delta = (x > 15.f) ? x : __logf(1.f + e);
      cum += delta;
      int p = dir_pix(k, s * 32 + t);
      float u = __bfloat162float(xcb[(bpix + p) * 384 + d]);
      float du = delta * u;
      const float4* Bq = (const float4*)(BsS + (lb + t) * 16);
      float4 b0 = Bq[0], b1 = Bq[1], b2 = Bq[2], b3 = Bq[3];
      float Bl[16] = {b0.x, b0.y, b0.z, b0.w, b1.x, b1.y, b1.z, b1.w,
                      b2.x, b2.y, b2.z, b2.w, b3.x, b3.y, b3.z, b3.w};
      #pragma unroll
      for (int n = 0; n < 16; n++) {
        float dA = __expf(delta * av[n]);
        h[n] = dA * h[n] + du * Bl[n];
      }
    }
  }
  long g = (long)bk * 128 + s;
  float* Ep = Eb + g * 6144 + d * 16;
  #pragma unroll
  for (int n = 0; n < 16; n++) Ep[n] = h[n];
  Dend[g * 384 + d] = cum;
}

// ---------------- combine: serial over 128 segments, h_in written in-place into Eb ----------------
__global__ __launch_bounds__(256) void k_combine(float* __restrict__ Eb,
                                                 const float* __restrict__ Dend,
                                                 const float* __restrict__ A_logs) {
  int t = blockIdx.x * 256 + threadIdx.x;  // B*K*6144 = 49152
  int bk = t / 6144;
  int dn = t - bk * 6144;
  int k = bk & 3;
  int d = dn >> 4;
  float av = -__expf(A_logs[(long)k * 6144 + dn]);
  float h = 0.f;
  long ebase = (long)bk * 128 * 6144 + dn;
  long dbase = (long)bk * 128 * 384 + d;
  for (int s = 0; s < 128; s++) {
    long ei = ebase + (long)s * 6144;
    float e = Eb[ei];
    float cum = Dend[dbase + (long)s * 384];
    Eb[ei] = h;                       // h_in for segment s (in-place)
    h = __expf(av * cum) * h + e;
  }
}

// ---------------- scan pass 1: full recurrence from h_in (in Eb), atomicAdd y ----------------
__global__ __launch_bounds__(384) void k_scan1(
    const float* __restrict__ dtsS, const float* __restrict__ BsS,
    const float* __restrict__ CsS, const __hip_bfloat16* __restrict__ xcb,
    const float* __restrict__ A_logs, const float* __restrict__ dt_w,
    const float* __restrict__ dt_b, const float* __restrict__ Eb,
    float* __restrict__ ysum) {
  int bid = blockIdx.x;
  int s = bid & 127, bk = bid >> 7;
  int k = bk & 3, b = bk >> 2;
  int d = threadIdx.x;
  float w[12];
  const float* dwp = dt_w + ((long)(k * 384) + d) * 12;
  #pragma unroll
  for (int r = 0; r < 12; r++) w[r] = dwp[r];
  float db = dt_b[k * 384 + d];
  const float* al = A_logs + ((long)(k * 384) + d) * 16;
  bool pw = true;
  float av[16];
  #pragma unroll
  for (int n = 0; n < 16; n++) {
    float a = __expf(al[n]);
    av[n] = -a;
    pw = pw && (fabsf(a - (float)(n + 1)) < 1e-3f);
  }
  float h[16];
  const float* hp = Eb + ((long)bk * 128 + s) * 6144 + d * 16;
  #pragma unroll
  for (int n = 0; n < 16; n++) h[n] = hp[n];
  long lb = (long)bk * 4096 + s * 32;
  long bpix = (long)(b << 12);

  if (pw) {
    #pragma unroll 4
    for (int t = 0; t < 32; t++) {
      const float4* dq = (const float4*)(dtsS + (lb + t) * 12);
      float4 q0 = dq[0], q1 = dq[1], q2 = dq[2];
      float x = db + q0.x * w[0] + q0.y * w[1] + q0.z * w[2] + q0.w * w[3]
                   + q1.x * w[4] + q1.y * w[5] + q1.z * w[6] + q1.w * w[7]
                   + q2.x * w[8] + q2.y * w[9] + q2.z * w[10] + q2.w * w[11];
      float e = __expf(x);
      float delta = (x > 15.f) ? x : __logf(1.f + e);
      int p = dir_pix(k, s * 32 + t);
      float u = __bfloat162float(xcb[(bpix + p) * 384 + d]);
      float du = delta * u;
      float rr = __builtin_amdgcn_rcpf(1.f + e);
      float pws[16]; pow16(rr, pws);
      const float4* Bq = (const float4*)(BsS + (lb + t) * 16);
      float4 b0 = Bq[0], b1 = Bq[1], b2 = Bq[2], b3 = Bq[3];
      float Bl[16] = {b0.x, b0.y, b0.z, b0.w, b1.x, b1.y, b1.z, b1.w,
                      b2.x, b2.y, b2.z, b2.w, b3.x, b3.y, b3.z, b3.w};
      const float4* Cq = (const float4*)(CsS + (lb + t) * 16);
      float4 c0 = Cq[0], c1 = Cq[1], c2 = Cq[2], c3 = Cq[3];
      float Cl[16] = {c0.x, c0.y, c0.z, c0.w, c1.x, c1.y, c1.z, c1.w,
                      c2.x, c2.y, c2.z, c2.w, c3.x, c3.y, c3.z, c3.w};
      float y = 0.f;
      #pragma unroll
      for (int n = 0; n < 16; n++) { h[n] = pws[n] * h[n] + du * Bl[n]; y += h[n] * Cl[n]; }
      atomicAdd(&ysum[(bpix + p) * 384 + d], y);
    }
  } else {
    for (int t = 0; t < 32; t++) {
      const float4* dq = (const float4*)(dtsS + (lb + t) * 12);
      float4 q0 = dq[0], q1 = dq[1], q2 = dq[2];
      float x = db + q0.x * w[0] + q0.y * w[1] + q0.z * w[2] + q0.w * w[3]
                   + q1.x * w[4] + q1.y * w[5] + q1.z * w[6] + q1.w * w[7]
                   + q2.x * w[8] + q2.y * w[9] + q2.z * w[10] + q2.w * w[11];
      float e = __expf(x);
      float delta = (x > 15.f) ? x : __logf(1.f + e);
      int p = dir_pix(k, s * 32 + t);
      float u = __bfloat162float(xcb[(bpix + p) * 384 + d]);
      float du = delta * u;
      const float4* Bq = (const float4*)(BsS + (lb + t) * 16);
      float4 b0 = Bq[0], b1 = Bq[1], b2 = Bq[2], b3 = Bq[3];
      float Bl[16] = {b0.x, b0.y, b0.z, b0.w, b1.x, b1.y, b1.z, b1.w,
                      b2.x, b2.y, b2.z, b2.w, b3.x, b3.y, b3.z, b3.w};
      const float4* Cq = (const float4*)(CsS + (lb + t) * 16);
      float4 c0 = Cq[0], c1 = Cq[1], c2 = Cq[2], c3 = Cq[3];
      float Cl[16] = {c0.x, c0.y, c0.z, c0.w, c1.x, c1.y, c1.z, c1.w,
                      c2.x, c2.y, c2.z, c2.w, c3.x, c3.y, c3.z, c3.w};
      float y = 0.f;
      #pragma unroll
      for (int n = 0; n < 16; n++) {
        float dA = __expf(delta * av[n]);
        h[n] = dA * h[n] + du * Bl[n];
        y += h[n] * Cl[n];
      }
      atomicAdd(&ysum[(bpix + p) * 384 + d], y);
    }
  }
}

// ---------------- merge: ysum + D-skip(bf16 xcb) + out-LN + silu(z bf16) -> bf16 ----------------
__global__ __launch_bounds__(384) void k_merge(const float* __restrict__ ysum,
                                               const __hip_bfloat16* __restrict__ xcb,
                                               const __hip_bfloat16* __restrict__ zbufB,
                                               const float* __restrict__ Ds,
                                               const float* __restrict__ g,
                                               const float* __restrict__ be,
                                               __hip_bfloat16* __restrict__ yactb) {
  int row = blockIdx.x;
  int d = threadIdx.x;
  float v = ysum[(long)row * 384 + d];
  float sd = Ds[d] + Ds[384 + d] + Ds[768 + d] + Ds[1152 + d];
  v += __bfloat162float(xcb[(long)row * 384 + d]) * sd;
  float s1 = v, s2 = v * v;
  #pragma unroll
  for (int o = 32; o > 0; o >>= 1) { s1 += __shfl_xor(s1, o); s2 += __shfl_xor(s2, o); }
  __shared__ float r1[6], r2[6];
  int wv = threadIdx.x >> 6;
  if ((threadIdx.x & 63) == 0) { r1[wv] = s1; r2[wv] = s2; }
  __syncthreads();
  float S1 = 0.f, S2 = 0.f;
  #pragma unroll
  for (int i = 0; i < 6; i++) { S1 += r1[i]; S2 += r2[i]; }
  float mu = S1 * (1.f / 384.f);
  float var = S2 * (1.f / 384.f) - mu * mu;
  float rr = rsqrtf(var + 1e-5f);
  float yn = (v - mu) * rr * g[d] + be[d];
  float z = __bfloat162float(zbufB[(long)row * 384 + d]);
  float sg = z / (1.f + __expf(-z));
  yactb[(long)row * 384 + d] = __float2bfloat16(yn * sg);
}

extern "C" void kernel_launch(void* const* d_in, const int* in_sizes, int n_in,
                              void* d_out, int out_size, void* d_ws, size_t ws_size,
                              hipStream_t stream) {
  const float* input      = (const float*)d_in[0];
  const float* norm_g     = (const float*)d_in[1];
  const float* norm_b     = (const float*)d_in[2];
  const float* in_proj_w  = (const float*)d_in[3];
  const float* conv_w     = (const float*)d_in[4];
  const float* conv_b     = (const float*)d_in[5];
  const float* x_proj_w   = (const float*)d_in[6];
  const float* dt_w       = (const float*)d_in[7];
  const float* dt_b       = (const float*)d_in[8];
  const float* A_logs     = (const float*)d_in[9];
  const float* Ds         = (const float*)d_in[10];
  const float* out_norm_g = (const float*)d_in[11];
  const float* out_norm_b = (const float*)d_in[12];
  const float* out_proj_w = (const float*)d_in[13];
  float* out = (float*)d_out;

  float* ws = (float*)d_ws;
  long o = 0;
  __hip_bfloat16* xnb   = (__hip_bfloat16*)(ws + o); o += 786432;   // 8192x192 bf16 (3.1MB)
  __hip_bfloat16* xbufB = (__hip_bfloat16*)(ws + o); o += 1572864;  // 8192x384 bf16
  __hip_bfloat16* zbufB = (__hip_bfloat16*)(ws + o); o += 1572864;
  __hip_bfloat16* xcb   = (__hip_bfloat16*)(ws + o); o += 1572864;
  __hip_bfloat16* Wt1   = (__hip_bfloat16*)(ws + o); o += 73728;    // 768x192 bf16
  __hip_bfloat16* Wt2   = (__hip_bfloat16*)(ws + o); o += 36864;    // 192x384 bf16
  __hip_bfloat16* Wt3   = (__hip_bfloat16*)(ws + o); o += 36864;
  float* dtsS           = ws + o;                    o += 393216;   // (BK,L,12)
  float* BsS            = ws + o;                    o += 524288;   // (BK,L,16)
  float* CsS            = ws + o;                    o += 524288;
  float* Eb             = ws + o;                    o += 6291456;  // (1024 segs, 6144): E then h_in
  float* Dend           = ws + o;                    o += 393216;   // (1024, 384)
  float* ysum           = ws + o;                    o += 3145728;  // (B,L,384) fp32
  __hip_bfloat16* yactb = (__hip_bfloat16*)(ws + o); o += 1572864;
  // total ≈ 18.5M floats ≈ 74 MB

  k_ln<<<dim3(2048), dim3(256), 0, stream>>>(input, norm_g, norm_b, xnb);
  k_packw<<<dim3(1152), dim3(256), 0, stream>>>(in_proj_w, x_proj_w, out_proj_w, Wt1, Wt2, Wt3);
  // in_proj: (8192x192)@(192x768), split bf16 epilogue -> xbufB/zbufB; grid 12x128
  k_gemm_mfma<2><<<dim3(12, 128), dim3(256), 0, stream>>>(xnb, Wt1, nullptr, nullptr, xbufB, zbufB,
                                                          nullptr, nullptr, nullptr, 8192, 768, 192);
  k_conv<<<dim3(8192), dim3(384), 0, stream>>>(xbufB, conv_w, conv_b, xcb);
  // x_proj: (8192x384)@(384x192), scatter epilogue -> dtsS/BsS/CsS; grid 3x128
  k_gemm_mfma<3><<<dim3(3, 128), dim3(256), 0, stream>>>(xcb, Wt2, nullptr, nullptr, nullptr, nullptr,
                                                         dtsS, BsS, CsS, 8192, 192, 384);
  k_scan0<<<dim3(1024), dim3(384), 0, stream>>>(dtsS, BsS, xcb, A_logs, dt_w, dt_b, Eb, Dend);
  k_combine<<<dim3(192), dim3(256), 0, stream>>>(Eb, Dend, A_logs);
  hipMemsetAsync(ysum, 0, 3145728 * sizeof(float), stream);
  k_scan1<<<dim3(1024), dim3(384), 0, stream>>>(dtsS, BsS, CsS, xcb, A_logs, dt_w, dt_b, Eb, ysum);
  k_merge<<<dim3(8192), dim3(384), 0, stream>>>(ysum, xcb, zbufB, Ds, out_norm_g, out_norm_b, yactb);
  // out_proj + residual: (8192x384)@(384x192) + input; grid 3x128
  k_gemm_mfma<1><<<dim3(3, 128), dim3(256), 0, stream>>>(yactb, Wt3, input, out, nullptr, nullptr,
                                                         nullptr, nullptr, nullptr, 8192, 192, 384);
}